// Round 5
// baseline (96.998 us; speedup 1.0000x reference)
//
#include <hip/hip_runtime.h>

// Block-factorized depthwise 7x7 conv, per-(n,c,8x8-block) filters.
// feat: [N=2, C=128, H=256, W=256] f32 (NCHW)
// filters_lr: [N, C*49, 32, 32] f32 ; weight[n,hb,wb,c,t] = filt[n, c*49+t, hb, wb]
// out[n,c,h,w] = sum_t feat[n,c,h+dh-3,w+dw-3] * weight[n,h/8,w/8,c,t], t=dh*7+dw
//
// NO LDS, NO barrier. Block = 256 threads = 16 output rows x 256 cols.
// Thread = 4 rows x 4 cols: 49 weights in VGPRs (coalesced 128B line per tap
// per wave, lane pairs share) + 10 input rows read as 3 aligned float4 global
// loads each (L1/L2 absorb the 2.2x overlap re-read; unique HBM bytes
// unchanged). ~30 independent VMEM loads in flight per thread -> latency
// hidden by ILP instead of a barrier-synchronized staging phase (round 4's
// residual serializer). Lane 0 / lane 63 column edges via predicated zero4;
// row edges via wave-uniform predicate.

__global__ __launch_bounds__(256, 2)
void block_fac_kernel(const float* __restrict__ feat,
                      const float* __restrict__ filt,
                      float* __restrict__ out) {
    const int bid = blockIdx.x;           // n*128*16 + c*16 + hb2
    const int hb2 = bid & 15;
    const int c   = (bid >> 4) & 127;
    const int n   = bid >> 11;
    const int tid = threadIdx.x;

    const int lane = tid & 63;
    const int wave = tid >> 6;
    const int c0   = lane << 2;           // output col base (0..252)
    const int wb   = lane >> 1;           // weight block col (0..31)
    const int r0   = wave << 2;           // output row base in tile (0,4,8,12)
    const int hb   = hb2 * 2 + (wave >> 1);  // weight block row

    // ---- weights: global -> VGPR, one coalesced 128B line per tap per wave
    const float* wgbase = filt + (size_t)((n * 128 + c) * 49) * 1024 + hb * 32 + wb;
    float wt[49];
    #pragma unroll
    for (int t = 0; t < 49; ++t) wt[t] = wgbase[(size_t)t * 1024];

    const int H0 = hb2 * 16;              // first output row of the tile
    const float* fbase = feat + (size_t)(n * 128 + c) * (256 * 256);

    const bool okL = (c0 >= 4);           // lane 0 left edge
    const bool okR = (c0 <= 248);         // lane 63 right edge
    const float4 z4 = make_float4(0.f, 0.f, 0.f, 0.f);

    float acc[4][4] = {};

    #pragma unroll
    for (int jj = 0; jj < 10; ++jj) {     // input row (H0+r0-3)+jj ; out row a uses dh=jj-a
        const int gr = H0 + r0 - 3 + jj;  // wave-uniform
        float4 L = z4, M = z4, R = z4;
        if (gr >= 0 && gr < 256) {        // uniform branch
            const float* rp = fbase + (size_t)gr * 256 + c0;
            M = *(const float4*)(rp);
            L = okL ? *(const float4*)(rp - 4) : z4;
            R = okR ? *(const float4*)(rp + 4) : z4;
        }
        // win[k] = feat col c0 + k - 4  (zeros outside [0,256))
        float win[12] = {L.x, L.y, L.z, L.w,
                         M.x, M.y, M.z, M.w,
                         R.x, R.y, R.z, R.w};
        #pragma unroll
        for (int a = 0; a < 4; ++a) {
            int dh = jj - a;
            if (dh >= 0 && dh <= 6) {
                #pragma unroll
                for (int dw = 0; dw < 7; ++dw) {
                    float wv = wt[dh * 7 + dw];
                    #pragma unroll
                    for (int i = 0; i < 4; ++i)
                        acc[a][i] += win[i + dw + 1] * wv;   // col c0+i+dw-3
                }
            }
        }
    }

    float* obase = out + (size_t)((n * 128 + c) * 256 + H0 + r0) * 256 + c0;
    #pragma unroll
    for (int a = 0; a < 4; ++a)
        *(float4*)(obase + (size_t)(a * 256)) =
            make_float4(acc[a][0], acc[a][1], acc[a][2], acc[a][3]);
}

extern "C" void kernel_launch(void* const* d_in, const int* in_sizes, int n_in,
                              void* d_out, int out_size, void* d_ws, size_t ws_size,
                              hipStream_t stream) {
    const float* feat = (const float*)d_in[0];
    const float* filt = (const float*)d_in[1];
    float* out = (float*)d_out;
    dim3 grid(2 * 128 * 16);
    dim3 block(256);
    hipLaunchKernelGGL(block_fac_kernel, grid, block, 0, stream, feat, filt, out);
}